// Round 2
// baseline (2002.116 us; speedup 1.0000x reference)
//
#include <hip/hip_runtime.h>
#include <hip/hip_bf16.h>
#include <stdint.h>

typedef unsigned short u16;
typedef unsigned int u32;
typedef __attribute__((ext_vector_type(4))) float f32x4;
typedef __attribute__((ext_vector_type(8))) short s16x8;
typedef __attribute__((ext_vector_type(4))) u32 u32x4;

#define DEV __device__ __forceinline__
#define AS1 __attribute__((address_space(1)))
#define AS3 __attribute__((address_space(3)))

// x: (8,64,64,768) flat tokens T2=32768. ws=14 windows; pads handled analytically
// (pad k == 0 exactly -> logit 0; pad v == v_b exactly; pad queries discarded).
constexpr int T2 = 8 * 64 * 64;
constexpr int C = 768;
constexpr int HID = 2048;
constexpr int CHUNK = 8192;  // FFN row chunk

DEV float blo(u32 u) { return __uint_as_float(u << 16); }
DEV float bhi(u32 u) { return __uint_as_float(u & 0xffff0000u); }
DEV u16 f2bf(float f) {
  u32 x = __float_as_uint(f);
  u32 r = x + 0x7fffu + ((x >> 16) & 1u);
  return (u16)(r >> 16);
}
DEV u32 pack2(float a, float b) { return (u32)f2bf(a) | ((u32)f2bf(b) << 16); }

DEV void reduce2(float& s, float& q) {
#pragma unroll
  for (int o = 32; o > 0; o >>= 1) {
    s += __shfl_down(s, o);
    q += __shfl_down(q, o);
  }
  __shared__ float ps[8];
  int wave = threadIdx.x >> 6, lane = threadIdx.x & 63;
  if (lane == 0) { ps[wave] = s; ps[4 + wave] = q; }
  __syncthreads();
  s = ps[0] + ps[1] + ps[2] + ps[3];
  q = ps[4] + ps[5] + ps[6] + ps[7];
}

// dst[n*K+k] = bf16(src[k*N+n])
__global__ void transpose_cvt_k(const float* __restrict__ src, u16* __restrict__ dst,
                                int K, int N) {
  int i = blockIdx.x * 256 + threadIdx.x;
  if (i >= K * N) return;
  int n = i / K, kk = i - n * K;
  dst[i] = f2bf(src[(size_t)kk * N + n]);
}

// rope tables ct/st [196][64]
__global__ void rope_tables_k(float* __restrict__ ct, float* __restrict__ st) {
  int i = blockIdx.x * 256 + threadIdx.x;
  if (i >= 196 * 32) return;
  int n = i >> 5, jp = i & 31;
  int d = jp << 1;
  int r = n / 14, c = n - r * 14;
  float pos, fj;
  if (d < 32) { pos = (float)r * (16.f / 14.f); fj = (float)(d >> 1); }
  else        { pos = (float)c * (16.f / 14.f); fj = (float)((d - 32) >> 1); }
  float fr = __expf(fj * (-2.f / 32.f) * logf(10000.f));
  float ang = pos * fr;
  float cv = cosf(ang), sv = sinf(ang);
  ct[n * 64 + d] = cv; ct[n * 64 + d + 1] = cv;
  st[n * 64 + d] = sv; st[n * 64 + d + 1] = sv;
}

// LN rows of 768: f32 in -> bf16 out
__global__ __launch_bounds__(256) void ln_k(const float* __restrict__ in,
    const float* __restrict__ w, const float* __restrict__ bb, u16* __restrict__ out) {
  size_t row = blockIdx.x;
  int tid = threadIdx.x;
  const float* xr = in + row * C;
  float v0 = xr[tid], v1 = xr[tid + 256], v2 = xr[tid + 512];
  float s = v0 + v1 + v2, q = v0 * v0 + v1 * v1 + v2 * v2;
  reduce2(s, q);
  float mu = s * (1.f / 768.f), var = q * (1.f / 768.f) - mu * mu;
  float rs = rsqrtf(var + 1e-6f);
  u16* orow = out + row * C;
  orow[tid]       = f2bf((v0 - mu) * rs * w[tid]       + bb[tid]);
  orow[tid + 256] = f2bf((v1 - mu) * rs * w[tid + 256] + bb[tid + 256]);
  orow[tid + 512] = f2bf((v2 - mu) * rs * w[tid + 512] + bb[tid + 512]);
}

// ---- bf16 MFMA GEMM: Cout[M,Nn] = A[M,K] * Bt[Nn,K]^T, 128x128 tile, BK=64 ----
// EPI 0: +bias -> bf16 ; EPI 2: +bias +resid -> f32
template <int EPI>
__global__ __launch_bounds__(256) void gemm_k(
    const u16* __restrict__ A, const u16* __restrict__ Bt,
    const float* __restrict__ bias, void* __restrict__ Cout,
    const float* __restrict__ resid, int M, int Nn, int K) {
  __shared__ u16 As[128 * 64];
  __shared__ u16 Bs[128 * 64];
  const int tid = threadIdx.x;
  const int wave = tid >> 6, lane = tid & 63;
  const int wm = wave >> 1, wn = wave & 1;
  const int tm = blockIdx.x, tn = blockIdx.y;
  const int l16 = lane & 15, lq = lane >> 4;

  f32x4 acc[4][4];
#pragma unroll
  for (int a = 0; a < 4; ++a)
#pragma unroll
    for (int b = 0; b < 4; ++b)
#pragma unroll
      for (int e = 0; e < 4; ++e) acc[a][b][e] = 0.f;

  const int nk = K >> 6;
  for (int kt = 0; kt < nk; ++kt) {
    const int k0 = kt << 6;
#pragma unroll
    for (int i = 0; i < 4; ++i) {
      int row = (((wave << 2) + i) << 3) + (lane >> 3);
      int cl = (lane & 7) ^ (row & 7);  // pre-swizzled source chunk (m173 pattern)
      const u16* sa = A + (size_t)(tm * 128 + row) * K + k0 + cl * 8;
      __builtin_amdgcn_global_load_lds((const AS1 u32*)sa,
          (AS3 u32*)(As + (((wave << 2) + i) << 9)), 16, 0, 0);
      const u16* sb = Bt + (size_t)(tn * 128 + row) * K + k0 + cl * 8;
      __builtin_amdgcn_global_load_lds((const AS1 u32*)sb,
          (AS3 u32*)(Bs + (((wave << 2) + i) << 9)), 16, 0, 0);
    }
    asm volatile("s_waitcnt vmcnt(0)" ::: "memory");
    __syncthreads();
#pragma unroll
    for (int ks = 0; ks < 2; ++ks) {
      s16x8 af[4], bfr[4];
#pragma unroll
      for (int mf = 0; mf < 4; ++mf) {
        int row = (wm << 6) + (mf << 4) + l16;
        int sc = ((ks << 2) + lq) ^ (row & 7);
        af[mf] = *(const s16x8*)(As + row * 64 + sc * 8);
      }
#pragma unroll
      for (int nf = 0; nf < 4; ++nf) {
        int row = (wn << 6) + (nf << 4) + l16;
        int sc = ((ks << 2) + lq) ^ (row & 7);
        bfr[nf] = *(const s16x8*)(Bs + row * 64 + sc * 8);
      }
#pragma unroll
      for (int mf = 0; mf < 4; ++mf)
#pragma unroll
        for (int nf = 0; nf < 4; ++nf)
          acc[mf][nf] =
              __builtin_amdgcn_mfma_f32_16x16x32_bf16(af[mf], bfr[nf], acc[mf][nf], 0, 0, 0);
    }
    __syncthreads();
  }

  // C/D layout: col=lane&15, row=(lane>>4)*4+reg (m89-verified)
#pragma unroll
  for (int nf = 0; nf < 4; ++nf) {
    int col = (tn << 7) + (wn << 6) + (nf << 4) + l16;
    float bs = bias ? bias[col] : 0.f;
#pragma unroll
    for (int mf = 0; mf < 4; ++mf) {
      int rbase = (tm << 7) + (wm << 6) + (mf << 4) + (lq << 2);
#pragma unroll
      for (int j = 0; j < 4; ++j) {
        int r = rbase + j;
        if (r >= M) continue;
        float val = acc[mf][nf][j] + bs;
        if constexpr (EPI == 0) {
          ((u16*)Cout)[(size_t)r * Nn + col] = f2bf(val);
        } else {
          ((float*)Cout)[(size_t)r * Nn + col] = resid[(size_t)r * Nn + col] + val;
        }
      }
    }
  }
}

// RoPE in-place on flat q (scale folded) and k
__global__ __launch_bounds__(256) void rope_apply_k(u16* __restrict__ q, u16* __restrict__ k,
    const float* __restrict__ ct, const float* __restrict__ st) {
  int i = blockIdx.x * 256 + threadIdx.x;
  if (i >= T2 * 384) return;
  int t = i / 384, p = i - t * 384;
  int h = p >> 5, pr = p & 31;
  int d = pr << 1;
  int rem = t & 4095;
  int gh = rem >> 6, gw = rem & 63;
  int n = (gh % 14) * 14 + (gw % 14);  // window-local position
  float c = ct[n * 64 + d], s = st[n * 64 + d];
  size_t e = (size_t)t * C + (h << 6) + d;
  u32* qp = (u32*)(q + e);
  u32 uq = *qp;
  float q0 = blo(uq), q1 = bhi(uq);
  *qp = pack2((q0 * c - q1 * s) * 0.125f, (q1 * c + q0 * s) * 0.125f);
  u32* kp = (u32*)(k + e);
  u32 uk = *kp;
  float k0 = blo(uk), k1 = bhi(uk);
  *kp = pack2(k0 * c - k1 * s, k1 * c + k0 * s);
}

// attention: block = (window, head); thread = one valid query row; pads analytic.
// writes o in-place over q (each thread only touches its own q row).
__global__ __launch_bounds__(256) void attn_k(u16* __restrict__ q,
    const u16* __restrict__ k, const u16* __restrict__ v,
    const float* __restrict__ vb) {
  __shared__ u16 Ks[196 * 64];
  __shared__ u16 Vs[196 * 64];
  __shared__ float vbs[64];
  int wid = blockIdx.x / 12, h = blockIdx.x - wid * 12;
  int bi = wid / 25, wr = wid - bi * 25;
  int hi = wr / 5, wj = wr - hi * 5;
  int rh = (hi == 4) ? 8 : 14, rw = (wj == 4) ? 8 : 14;
  int nv = rh * rw;
  int tid = threadIdx.x;
  if (tid < 64) vbs[tid] = vb[h * 64 + tid];
  for (int idx = tid; idx < nv * 8; idx += 256) {
    int row = idx >> 3, c = idx & 7;
    int nr = row / rw, nc = row - nr * rw;
    size_t fl = ((size_t)bi * 64 + hi * 14 + nr) * 64 + (wj * 14 + nc);
    size_t off = fl * C + (h << 6) + c * 8;
    *(u32x4*)(Ks + idx * 8) = *(const u32x4*)(k + off);
    *(u32x4*)(Vs + idx * 8) = *(const u32x4*)(v + off);
  }
  __syncthreads();
  if (tid >= nv) return;
  int nr = tid / rw, nc = tid - nr * rw;
  size_t fl = ((size_t)bi * 64 + hi * 14 + nr) * 64 + (wj * 14 + nc);
  u16* qrow = q + fl * C + (h << 6);
  float qr[64];
  {
    const u32x4* qp = (const u32x4*)qrow;
#pragma unroll
    for (int c = 0; c < 8; ++c) {
      u32x4 u = qp[c];
      qr[c * 8 + 0] = blo(u.x); qr[c * 8 + 1] = bhi(u.x);
      qr[c * 8 + 2] = blo(u.y); qr[c * 8 + 3] = bhi(u.y);
      qr[c * 8 + 4] = blo(u.z); qr[c * 8 + 5] = bhi(u.z);
      qr[c * 8 + 6] = blo(u.w); qr[c * 8 + 7] = bhi(u.w);
    }
  }
  float acc[64];
#pragma unroll
  for (int d = 0; d < 64; ++d) acc[d] = 0.f;
  float mr = -3.0e38f, lr = 0.f;
  for (int mk = 0; mk < nv; ++mk) {
    const u32* kr = (const u32*)(Ks + mk * 64);
    float s = 0.f;
#pragma unroll
    for (int j = 0; j < 32; ++j) {
      u32 u = kr[j];
      s = fmaf(qr[2 * j], blo(u), s);
      s = fmaf(qr[2 * j + 1], bhi(u), s);
    }
    float mn = fmaxf(mr, s);
    float p = __expf(s - mn);
    float cor = __expf(mr - mn);
    mr = mn;
    lr = lr * cor + p;
    const u32* vr = (const u32*)(Vs + mk * 64);
#pragma unroll
    for (int j = 0; j < 32; ++j) {
      u32 u = vr[j];
      acc[2 * j]     = fmaf(p, blo(u), acc[2 * j] * cor);
      acc[2 * j + 1] = fmaf(p, bhi(u), acc[2 * j + 1] * cor);
    }
  }
  int P = 196 - nv;  // pad keys: logit exactly 0, value exactly v_b
  if (P > 0) {
    float mn = fmaxf(mr, 0.f);
    float cor = __expf(mr - mn);
    float p = __expf(0.f - mn) * (float)P;
    mr = mn;
    lr = lr * cor + p;
#pragma unroll
    for (int d = 0; d < 64; ++d) acc[d] = acc[d] * cor + p * vbs[d];
  }
  float inv = 1.f / lr;
  u32x4* op = (u32x4*)qrow;
#pragma unroll
  for (int c = 0; c < 8; ++c) {
    u32x4 u;
    u.x = pack2(acc[c * 8 + 0] * inv, acc[c * 8 + 1] * inv);
    u.y = pack2(acc[c * 8 + 2] * inv, acc[c * 8 + 3] * inv);
    u.z = pack2(acc[c * 8 + 4] * inv, acc[c * 8 + 5] * inv);
    u.w = pack2(acc[c * 8 + 6] * inv, acc[c * 8 + 7] * inv);
    op[c] = u;
  }
}

// SwiGLU + LN over 2048 (in-place safe)
__global__ __launch_bounds__(256) void swiglu_ln_k(const u16* __restrict__ h1,
    const u16* __restrict__ h2, const float* __restrict__ w, const float* __restrict__ bb,
    u16* __restrict__ out) {
  size_t row = blockIdx.x;
  int tid = threadIdx.x;
  const u32x4 ua = *(const u32x4*)(h1 + row * HID + tid * 8);
  const u32x4 ub = *(const u32x4*)(h2 + row * HID + tid * 8);
  u32 pa[4] = {ua.x, ua.y, ua.z, ua.w};
  u32 pb[4] = {ub.x, ub.y, ub.z, ub.w};
  float g[8];
  float s = 0.f, qq = 0.f;
#pragma unroll
  for (int j = 0; j < 4; ++j) {
    float a0 = blo(pa[j]), a1 = bhi(pa[j]);
    float b0 = blo(pb[j]), b1 = bhi(pb[j]);
    float s0 = a0 / (1.f + __expf(-a0));
    float s1 = a1 / (1.f + __expf(-a1));
    g[2 * j] = s0 * b0; g[2 * j + 1] = s1 * b1;
    s += g[2 * j] + g[2 * j + 1];
    qq += g[2 * j] * g[2 * j] + g[2 * j + 1] * g[2 * j + 1];
  }
  reduce2(s, qq);
  float mu = s * (1.f / 2048.f);
  float var = qq * (1.f / 2048.f) - mu * mu;
  float rs = rsqrtf(var + 1e-6f);
  const float* wp = w + tid * 8;
  const float* bp = bb + tid * 8;
  u32 o4[4];
#pragma unroll
  for (int j = 0; j < 4; ++j) {
    float o0 = (g[2 * j] - mu) * rs * wp[2 * j] + bp[2 * j];
    float o1 = (g[2 * j + 1] - mu) * rs * wp[2 * j + 1] + bp[2 * j + 1];
    o4[j] = pack2(o0, o1);
  }
  *(u32x4*)(out + row * HID + tid * 8) = (u32x4){o4[0], o4[1], o4[2], o4[3]};
}

extern "C" void kernel_launch(void* const* d_in, const int* in_sizes, int n_in,
                              void* d_out, int out_size, void* d_ws, size_t ws_size,
                              hipStream_t stream) {
  const float* x    = (const float*)d_in[0];
  const float* ln1w = (const float*)d_in[1];
  const float* ln1b = (const float*)d_in[2];
  const float* qw   = (const float*)d_in[3];
  const float* qb   = (const float*)d_in[4];
  const float* kw   = (const float*)d_in[5];
  const float* vw   = (const float*)d_in[6];
  const float* vb   = (const float*)d_in[7];
  const float* pw   = (const float*)d_in[8];
  const float* pb   = (const float*)d_in[9];
  const float* ln2w = (const float*)d_in[10];
  const float* ln2b = (const float*)d_in[11];
  const float* w1   = (const float*)d_in[12];
  const float* w1b  = (const float*)d_in[13];
  const float* w2   = (const float*)d_in[14];
  const float* w2b  = (const float*)d_in[15];
  const float* ffw  = (const float*)d_in[16];
  const float* ffb  = (const float*)d_in[17];
  const float* w3   = (const float*)d_in[18];
  const float* w3b  = (const float*)d_in[19];

  char* ws = (char*)d_ws;
  size_t off = 0;
  auto alloc = [&](size_t bytes) -> char* {
    char* p = ws + off;
    off += (bytes + 255) & ~(size_t)255;
    return p;
  };
  u16* qwt = (u16*)alloc((size_t)768 * 768 * 2);
  u16* kwt = (u16*)alloc((size_t)768 * 768 * 2);
  u16* vwt = (u16*)alloc((size_t)768 * 768 * 2);
  u16* pwt = (u16*)alloc((size_t)768 * 768 * 2);
  u16* w1t = (u16*)alloc((size_t)2048 * 768 * 2);
  u16* w2t = (u16*)alloc((size_t)2048 * 768 * 2);
  u16* w3t = (u16*)alloc((size_t)768 * 2048 * 2);
  float* ct = (float*)alloc((size_t)196 * 64 * 4);
  float* st = (float*)alloc((size_t)196 * 64 * 4);
  u16* xw   = (u16*)alloc((size_t)T2 * C * 2);  // LN1 out; reused as h2 (LN2 out)
  u16* qbuf = (u16*)alloc((size_t)T2 * C * 2);  // q; attn out in-place; h1c chunk
  u16* kbuf = (u16*)alloc((size_t)T2 * C * 2);  // k; h2c chunk
  u16* vbuf = (u16*)alloc((size_t)T2 * C * 2);  // v
  // total ~216 MB
  u16* h2   = xw;
  u16* h1c  = qbuf;  // 8192*2048*2 = 33.5MB <= 50.3MB
  u16* h2c  = kbuf;
  float* x2 = (float*)d_out;  // f32 residual stream lives in d_out

  transpose_cvt_k<<<(768 * 768 + 255) / 256, 256, 0, stream>>>(qw, qwt, 768, 768);
  transpose_cvt_k<<<(768 * 768 + 255) / 256, 256, 0, stream>>>(kw, kwt, 768, 768);
  transpose_cvt_k<<<(768 * 768 + 255) / 256, 256, 0, stream>>>(vw, vwt, 768, 768);
  transpose_cvt_k<<<(768 * 768 + 255) / 256, 256, 0, stream>>>(pw, pwt, 768, 768);
  transpose_cvt_k<<<(768 * 2048 + 255) / 256, 256, 0, stream>>>(w1, w1t, 768, 2048);
  transpose_cvt_k<<<(768 * 2048 + 255) / 256, 256, 0, stream>>>(w2, w2t, 768, 2048);
  transpose_cvt_k<<<(768 * 2048 + 255) / 256, 256, 0, stream>>>(w3, w3t, 2048, 768);
  rope_tables_k<<<(196 * 32 + 255) / 256, 256, 0, stream>>>(ct, st);

  // attention half (flat tokens)
  ln_k<<<T2, 256, 0, stream>>>(x, ln1w, ln1b, xw);
  dim3 g1(T2 / 128, 6);
  gemm_k<0><<<g1, 256, 0, stream>>>(xw, qwt, qb, qbuf, nullptr, T2, 768, 768);
  gemm_k<0><<<g1, 256, 0, stream>>>(xw, kwt, nullptr, kbuf, nullptr, T2, 768, 768);
  gemm_k<0><<<g1, 256, 0, stream>>>(xw, vwt, vb, vbuf, nullptr, T2, 768, 768);
  rope_apply_k<<<(T2 * 384) / 256, 256, 0, stream>>>(qbuf, kbuf, ct, st);
  attn_k<<<200 * 12, 256, 0, stream>>>(qbuf, kbuf, vbuf, vb);
  gemm_k<2><<<g1, 256, 0, stream>>>(qbuf, pwt, pb, x2, x, T2, 768, 768);

  // FFN half, chunked to cap workspace
  ln_k<<<T2, 256, 0, stream>>>(x2, ln2w, ln2b, h2);
  for (int cidx = 0; cidx < T2 / CHUNK; ++cidx) {
    const u16* hrow = h2 + (size_t)cidx * CHUNK * C;
    dim3 g2(CHUNK / 128, 16);
    gemm_k<0><<<g2, 256, 0, stream>>>(hrow, w1t, w1b, h1c, nullptr, CHUNK, HID, 768);
    gemm_k<0><<<g2, 256, 0, stream>>>(hrow, w2t, w2b, h2c, nullptr, CHUNK, HID, 768);
    swiglu_ln_k<<<CHUNK, 256, 0, stream>>>(h1c, h2c, ffw, ffb, h1c);
    dim3 g3(CHUNK / 128, 6);
    gemm_k<2><<<g3, 256, 0, stream>>>(h1c, w3t, w3b, x2 + (size_t)cidx * CHUNK * C,
                                      x2 + (size_t)cidx * CHUNK * C, CHUNK, 768, 2048);
  }
}

// Round 3
// 1455.529 us; speedup vs baseline: 1.3755x; 1.3755x over previous
//
#include <hip/hip_runtime.h>
#include <hip/hip_bf16.h>
#include <stdint.h>

typedef unsigned short u16;
typedef unsigned int u32;
typedef __attribute__((ext_vector_type(4))) float f32x4;
typedef __attribute__((ext_vector_type(8))) short s16x8;
typedef __attribute__((ext_vector_type(4))) u32 u32x4;

#define DEV __device__ __forceinline__
#define AS1 __attribute__((address_space(1)))
#define AS3 __attribute__((address_space(3)))

// x: (8,64,64,768) flat tokens T2=32768. ws=14 windows; pads handled analytically
// (pad k == 0 exactly -> logit 0; pad v == v_b exactly; pad queries discarded).
constexpr int T2 = 8 * 64 * 64;
constexpr int C = 768;
constexpr int HID = 2048;
constexpr int CHUNK = 8192;  // FFN row chunk

DEV float blo(u32 u) { return __uint_as_float(u << 16); }
DEV float bhi(u32 u) { return __uint_as_float(u & 0xffff0000u); }
DEV u16 f2bf(float f) {
  u32 x = __float_as_uint(f);
  u32 r = x + 0x7fffu + ((x >> 16) & 1u);
  return (u16)(r >> 16);
}
DEV u32 pack2(float a, float b) { return (u32)f2bf(a) | ((u32)f2bf(b) << 16); }

DEV void reduce2(float& s, float& q) {
#pragma unroll
  for (int o = 32; o > 0; o >>= 1) {
    s += __shfl_down(s, o);
    q += __shfl_down(q, o);
  }
  __shared__ float ps[8];
  int wave = threadIdx.x >> 6, lane = threadIdx.x & 63;
  if (lane == 0) { ps[wave] = s; ps[4 + wave] = q; }
  __syncthreads();
  s = ps[0] + ps[1] + ps[2] + ps[3];
  q = ps[4] + ps[5] + ps[6] + ps[7];
}

// dst[n*K+k] = bf16(src[k*N+n])
__global__ void transpose_cvt_k(const float* __restrict__ src, u16* __restrict__ dst,
                                int K, int N) {
  int i = blockIdx.x * 256 + threadIdx.x;
  if (i >= K * N) return;
  int n = i / K, kk = i - n * K;
  dst[i] = f2bf(src[(size_t)kk * N + n]);
}

// rope tables ct/st [196][64]
__global__ void rope_tables_k(float* __restrict__ ct, float* __restrict__ st) {
  int i = blockIdx.x * 256 + threadIdx.x;
  if (i >= 196 * 32) return;
  int n = i >> 5, jp = i & 31;
  int d = jp << 1;
  int r = n / 14, c = n - r * 14;
  float pos, fj;
  if (d < 32) { pos = (float)r * (16.f / 14.f); fj = (float)(d >> 1); }
  else        { pos = (float)c * (16.f / 14.f); fj = (float)((d - 32) >> 1); }
  float fr = __expf(fj * (-2.f / 32.f) * logf(10000.f));
  float ang = pos * fr;
  float cv = cosf(ang), sv = sinf(ang);
  ct[n * 64 + d] = cv; ct[n * 64 + d + 1] = cv;
  st[n * 64 + d] = sv; st[n * 64 + d + 1] = sv;
}

// LN rows of 768: f32 in -> bf16 out
__global__ __launch_bounds__(256) void ln_k(const float* __restrict__ in,
    const float* __restrict__ w, const float* __restrict__ bb, u16* __restrict__ out) {
  size_t row = blockIdx.x;
  int tid = threadIdx.x;
  const float* xr = in + row * C;
  float v0 = xr[tid], v1 = xr[tid + 256], v2 = xr[tid + 512];
  float s = v0 + v1 + v2, q = v0 * v0 + v1 * v1 + v2 * v2;
  reduce2(s, q);
  float mu = s * (1.f / 768.f), var = q * (1.f / 768.f) - mu * mu;
  float rs = rsqrtf(var + 1e-6f);
  u16* orow = out + row * C;
  orow[tid]       = f2bf((v0 - mu) * rs * w[tid]       + bb[tid]);
  orow[tid + 256] = f2bf((v1 - mu) * rs * w[tid + 256] + bb[tid + 256]);
  orow[tid + 512] = f2bf((v2 - mu) * rs * w[tid + 512] + bb[tid + 512]);
}

// ---- bf16 MFMA GEMM: Cout[M,Nn] = A[M,K] * Bt[Nn,K]^T, 128x128 tile, BK=64 ----
// EPI 0: +bias -> bf16 ; EPI 2: +bias +resid -> f32
template <int EPI>
__global__ __launch_bounds__(256) void gemm_k(
    const u16* __restrict__ A, const u16* __restrict__ Bt,
    const float* __restrict__ bias, void* __restrict__ Cout,
    const float* __restrict__ resid, int M, int Nn, int K) {
  __shared__ u16 As[128 * 64];
  __shared__ u16 Bs[128 * 64];
  const int tid = threadIdx.x;
  const int wave = tid >> 6, lane = tid & 63;
  const int wm = wave >> 1, wn = wave & 1;
  const int tm = blockIdx.x, tn = blockIdx.y;
  const int l16 = lane & 15, lq = lane >> 4;

  f32x4 acc[4][4];
#pragma unroll
  for (int a = 0; a < 4; ++a)
#pragma unroll
    for (int b = 0; b < 4; ++b)
#pragma unroll
      for (int e = 0; e < 4; ++e) acc[a][b][e] = 0.f;

  const int nk = K >> 6;
  for (int kt = 0; kt < nk; ++kt) {
    const int k0 = kt << 6;
#pragma unroll
    for (int i = 0; i < 4; ++i) {
      int row = (((wave << 2) + i) << 3) + (lane >> 3);
      int cl = (lane & 7) ^ (row & 7);  // pre-swizzled source chunk (m173 pattern)
      const u16* sa = A + (size_t)(tm * 128 + row) * K + k0 + cl * 8;
      __builtin_amdgcn_global_load_lds((const AS1 u32*)sa,
          (AS3 u32*)(As + (((wave << 2) + i) << 9)), 16, 0, 0);
      const u16* sb = Bt + (size_t)(tn * 128 + row) * K + k0 + cl * 8;
      __builtin_amdgcn_global_load_lds((const AS1 u32*)sb,
          (AS3 u32*)(Bs + (((wave << 2) + i) << 9)), 16, 0, 0);
    }
    asm volatile("s_waitcnt vmcnt(0)" ::: "memory");
    __syncthreads();
#pragma unroll
    for (int ks = 0; ks < 2; ++ks) {
      s16x8 af[4], bfr[4];
#pragma unroll
      for (int mf = 0; mf < 4; ++mf) {
        int row = (wm << 6) + (mf << 4) + l16;
        int sc = ((ks << 2) + lq) ^ (row & 7);
        af[mf] = *(const s16x8*)(As + row * 64 + sc * 8);
      }
#pragma unroll
      for (int nf = 0; nf < 4; ++nf) {
        int row = (wn << 6) + (nf << 4) + l16;
        int sc = ((ks << 2) + lq) ^ (row & 7);
        bfr[nf] = *(const s16x8*)(Bs + row * 64 + sc * 8);
      }
#pragma unroll
      for (int mf = 0; mf < 4; ++mf)
#pragma unroll
        for (int nf = 0; nf < 4; ++nf)
          acc[mf][nf] =
              __builtin_amdgcn_mfma_f32_16x16x32_bf16(af[mf], bfr[nf], acc[mf][nf], 0, 0, 0);
    }
    __syncthreads();
  }

  // C/D layout: col=lane&15, row=(lane>>4)*4+reg (m89-verified)
#pragma unroll
  for (int nf = 0; nf < 4; ++nf) {
    int col = (tn << 7) + (wn << 6) + (nf << 4) + l16;
    float bs = bias ? bias[col] : 0.f;
#pragma unroll
    for (int mf = 0; mf < 4; ++mf) {
      int rbase = (tm << 7) + (wm << 6) + (mf << 4) + (lq << 2);
#pragma unroll
      for (int j = 0; j < 4; ++j) {
        int r = rbase + j;
        if (r >= M) continue;
        float val = acc[mf][nf][j] + bs;
        if constexpr (EPI == 0) {
          ((u16*)Cout)[(size_t)r * Nn + col] = f2bf(val);
        } else {
          ((float*)Cout)[(size_t)r * Nn + col] = resid[(size_t)r * Nn + col] + val;
        }
      }
    }
  }
}

// RoPE in-place on flat q (scale folded) and k
__global__ __launch_bounds__(256) void rope_apply_k(u16* __restrict__ q, u16* __restrict__ k,
    const float* __restrict__ ct, const float* __restrict__ st) {
  int i = blockIdx.x * 256 + threadIdx.x;
  if (i >= T2 * 384) return;
  int t = i / 384, p = i - t * 384;
  int h = p >> 5, pr = p & 31;
  int d = pr << 1;
  int rem = t & 4095;
  int gh = rem >> 6, gw = rem & 63;
  int n = (gh % 14) * 14 + (gw % 14);  // window-local position
  float c = ct[n * 64 + d], s = st[n * 64 + d];
  size_t e = (size_t)t * C + (h << 6) + d;
  u32* qp = (u32*)(q + e);
  u32 uq = *qp;
  float q0 = blo(uq), q1 = bhi(uq);
  *qp = pack2((q0 * c - q1 * s) * 0.125f, (q1 * c + q0 * s) * 0.125f);
  u32* kp = (u32*)(k + e);
  u32 uk = *kp;
  float k0 = blo(uk), k1 = bhi(uk);
  *kp = pack2(k0 * c - k1 * s, k1 * c + k0 * s);
}

// ---- MFMA attention: block = (window, head), 4 waves ----
// Waves split the <=13 M-tiles (16 q-rows each). KVBLK=32 online softmax.
// K staged [rows][64] XOR-swizzled; V staged transposed [64][224] XOR-swizzled.
// P routed through per-wave LDS [16][40] to convert C-layout -> A-frag layout.
// Pad keys in [nv, nk16*16) staged K=0/V=vb (matches reference); keys >=196
// masked p=0; pad keys beyond nk16*16 added analytically (logit 0, value vb).
__global__ __launch_bounds__(256) void attn_mfma_k(u16* __restrict__ q,
    const u16* __restrict__ k, const u16* __restrict__ v,
    const float* __restrict__ vb) {
  __shared__ u16 Ks[208 * 64];   // swizzled: byte = (key*128 + d*2) ^ ((key&7)<<4)
  __shared__ u16 Vt[64 * 224];   // swizzled: byte = (d*448 + key*2) ^ ((d&7)<<4)
  __shared__ u16 Pl[4 * 16 * 40];
  int wid = blockIdx.x / 12, h = blockIdx.x - wid * 12;
  int bi = wid / 25, wr = wid - bi * 25;
  int hi = wr / 5, wj = wr - hi * 5;
  int rh = (hi == 4) ? 8 : 14, rw = (wj == 4) ? 8 : 14;
  int nv = rh * rw;
  int nk16 = (nv + 15) >> 4;           // 16-key tiles run through MFMA
  int kvfull = nk16 >> 1;              // full 32-key steps
  int nsteps = kvfull + (nk16 & 1);
  int vcols = ((nk16 + 1) >> 1) << 5;  // Vt cols touched (incl. tail's zero-P half)
  int tid = threadIdx.x;
  int rowbase = (bi * 64 + hi * 14) * 64 + wj * 14;  // flat token of window (0,0)

  // stage K rows [0, nk16*16)
  for (int idx = tid; idx < nk16 * 128; idx += 256) {
    int key = idx >> 3, c = idx & 7;
    u32x4 val = {0, 0, 0, 0};
    if (key < nv) {
      int nr = key / rw, nc = key - nr * rw;
      size_t off = (size_t)(rowbase + nr * 64 + nc) * C + (h << 6) + c * 8;
      val = *(const u32x4*)(k + off);
    }
    int byte = (key * 128 + c * 16) ^ ((key & 7) << 4);
    *(u32x4*)(Ks + (byte >> 1)) = val;
  }
  // stage V transposed, cols [0, vcols)
  for (int idx = tid; idx < vcols * 32; idx += 256) {
    int key = idx >> 5, dp = idx & 31;
    int d = dp << 1;
    u32 val;
    if (key < nv) {
      int nr = key / rw, nc = key - nr * rw;
      size_t off = (size_t)(rowbase + nr * 64 + nc) * C + (h << 6) + d;
      val = *(const u32*)(v + off);
    } else {
      val = pack2(vb[(h << 6) + d], vb[(h << 6) + d + 1]);
    }
    int b0 = (d * 448 + key * 2) ^ ((d & 7) << 4);
    int b1 = ((d + 1) * 448 + key * 2) ^ (((d + 1) & 7) << 4);
    Vt[b0 >> 1] = (u16)(val & 0xffffu);
    Vt[b1 >> 1] = (u16)(val >> 16);
  }
  __syncthreads();

  int wave = tid >> 6, lane = tid & 63;
  int l16 = lane & 15, lq = lane >> 4;
  u16* Pw = Pl + wave * 640;
  float vbr[4];
#pragma unroll
  for (int dt = 0; dt < 4; ++dt) vbr[dt] = vb[(h << 6) + dt * 16 + l16];

  int mtiles = (nv + 15) >> 4;
  for (int mt = wave; mt < mtiles; mt += 4) {
    // Q A-frags (row = l16, k = lq*8.. contiguous)
    s16x8 a[2];
    {
      int qi = mt * 16 + l16;
      if (qi >= nv) qi = nv - 1;
      int nr = qi / rw, nc = qi - nr * rw;
      const u16* qp = q + (size_t)(rowbase + nr * 64 + nc) * C + (h << 6);
      a[0] = *(const s16x8*)(qp + lq * 8);
      a[1] = *(const s16x8*)(qp + 32 + lq * 8);
    }
    f32x4 O[4];
#pragma unroll
    for (int dt = 0; dt < 4; ++dt)
#pragma unroll
      for (int j = 0; j < 4; ++j) O[dt][j] = 0.f;
    float mrow[4] = {-3.0e38f, -3.0e38f, -3.0e38f, -3.0e38f};
    float lrow[4] = {0.f, 0.f, 0.f, 0.f};

    for (int kv = 0; kv < nsteps; ++kv) {
      const bool full = kv < kvfull;
      const int keyb = kv << 5;
      f32x4 s0 = {0.f, 0.f, 0.f, 0.f}, s1 = {0.f, 0.f, 0.f, 0.f};
      int key0 = keyb + l16, key1 = key0 + 16;
#pragma unroll
      for (int s = 0; s < 2; ++s) {
        int byte0 = (key0 * 128 + s * 64 + lq * 16) ^ ((key0 & 7) << 4);
        s16x8 b0 = *(const s16x8*)(Ks + (byte0 >> 1));
        s0 = __builtin_amdgcn_mfma_f32_16x16x32_bf16(a[s], b0, s0, 0, 0, 0);
        if (full) {
          int byte1 = (key1 * 128 + s * 64 + lq * 16) ^ ((key1 & 7) << 4);
          s16x8 b1 = *(const s16x8*)(Ks + (byte1 >> 1));
          s1 = __builtin_amdgcn_mfma_f32_16x16x32_bf16(a[s], b1, s1, 0, 0, 0);
        }
      }
      float pc[4];
#pragma unroll
      for (int j = 0; j < 4; ++j) {
        float mv = full ? fmaxf(s0[j], s1[j]) : s0[j];
        mv = fmaxf(mv, __shfl_xor(mv, 1));
        mv = fmaxf(mv, __shfl_xor(mv, 2));
        mv = fmaxf(mv, __shfl_xor(mv, 4));
        mv = fmaxf(mv, __shfl_xor(mv, 8));
        float nm = fmaxf(mrow[j], mv);
        pc[j] = __expf(mrow[j] - nm);
        mrow[j] = nm;
      }
#pragma unroll
      for (int j = 0; j < 4; ++j) {
        float p0 = (key0 < 196) ? __expf(s0[j] - mrow[j]) : 0.f;
        float p1 = (full && key1 < 196) ? __expf(s1[j] - mrow[j]) : 0.f;
        float rs = p0 + p1;
        rs += __shfl_xor(rs, 1);
        rs += __shfl_xor(rs, 2);
        rs += __shfl_xor(rs, 4);
        rs += __shfl_xor(rs, 8);
        lrow[j] = lrow[j] * pc[j] + rs;
        Pw[(lq * 4 + j) * 40 + l16] = f2bf(p0);
        Pw[(lq * 4 + j) * 40 + l16 + 16] = f2bf(p1);
      }
#pragma unroll
      for (int dt = 0; dt < 4; ++dt)
#pragma unroll
        for (int j = 0; j < 4; ++j) O[dt][j] *= pc[j];
      s16x8 pa = *(const s16x8*)(Pw + l16 * 40 + lq * 8);
#pragma unroll
      for (int dt = 0; dt < 4; ++dt) {
        int d = dt * 16 + l16;
        int vbyte = (d * 448 + keyb * 2 + lq * 16) ^ ((d & 7) << 4);
        s16x8 bv = *(const s16x8*)(Vt + (vbyte >> 1));
        O[dt] = __builtin_amdgcn_mfma_f32_16x16x32_bf16(pa, bv, O[dt], 0, 0, 0);
      }
    }
    // analytic remaining pad keys (logit 0, value vb)
    int Prem = 196 - (nk16 << 4);
    if (Prem > 0) {
#pragma unroll
      for (int j = 0; j < 4; ++j) {
        float nm = fmaxf(mrow[j], 0.f);
        float pc = __expf(mrow[j] - nm);
        float pp = __expf(-nm) * (float)Prem;
        lrow[j] = lrow[j] * pc + pp;
#pragma unroll
        for (int dt = 0; dt < 4; ++dt) O[dt][j] = O[dt][j] * pc + pp * vbr[dt];
      }
    }
    // write O in-place over q rows (C layout: row=lq*4+j, col=l16)
#pragma unroll
    for (int j = 0; j < 4; ++j) {
      int qi = mt * 16 + lq * 4 + j;
      if (qi < nv) {
        float inv = 1.f / lrow[j];
        int nr = qi / rw, nc = qi - nr * rw;
        u16* op = q + (size_t)(rowbase + nr * 64 + nc) * C + (h << 6);
#pragma unroll
        for (int dt = 0; dt < 4; ++dt) op[dt * 16 + l16] = f2bf(O[dt][j] * inv);
      }
    }
  }
}

// SwiGLU + LN over 2048 (in-place safe)
__global__ __launch_bounds__(256) void swiglu_ln_k(const u16* __restrict__ h1,
    const u16* __restrict__ h2, const float* __restrict__ w, const float* __restrict__ bb,
    u16* __restrict__ out) {
  size_t row = blockIdx.x;
  int tid = threadIdx.x;
  const u32x4 ua = *(const u32x4*)(h1 + row * HID + tid * 8);
  const u32x4 ub = *(const u32x4*)(h2 + row * HID + tid * 8);
  u32 pa[4] = {ua.x, ua.y, ua.z, ua.w};
  u32 pb[4] = {ub.x, ub.y, ub.z, ub.w};
  float g[8];
  float s = 0.f, qq = 0.f;
#pragma unroll
  for (int j = 0; j < 4; ++j) {
    float a0 = blo(pa[j]), a1 = bhi(pa[j]);
    float b0 = blo(pb[j]), b1 = bhi(pb[j]);
    float s0 = a0 / (1.f + __expf(-a0));
    float s1 = a1 / (1.f + __expf(-a1));
    g[2 * j] = s0 * b0; g[2 * j + 1] = s1 * b1;
    s += g[2 * j] + g[2 * j + 1];
    qq += g[2 * j] * g[2 * j] + g[2 * j + 1] * g[2 * j + 1];
  }
  reduce2(s, qq);
  float mu = s * (1.f / 2048.f);
  float var = qq * (1.f / 2048.f) - mu * mu;
  float rs = rsqrtf(var + 1e-6f);
  const float* wp = w + tid * 8;
  const float* bp = bb + tid * 8;
  u32 o4[4];
#pragma unroll
  for (int j = 0; j < 4; ++j) {
    float o0 = (g[2 * j] - mu) * rs * wp[2 * j] + bp[2 * j];
    float o1 = (g[2 * j + 1] - mu) * rs * wp[2 * j + 1] + bp[2 * j + 1];
    o4[j] = pack2(o0, o1);
  }
  *(u32x4*)(out + row * HID + tid * 8) = (u32x4){o4[0], o4[1], o4[2], o4[3]};
}

extern "C" void kernel_launch(void* const* d_in, const int* in_sizes, int n_in,
                              void* d_out, int out_size, void* d_ws, size_t ws_size,
                              hipStream_t stream) {
  const float* x    = (const float*)d_in[0];
  const float* ln1w = (const float*)d_in[1];
  const float* ln1b = (const float*)d_in[2];
  const float* qw   = (const float*)d_in[3];
  const float* qb   = (const float*)d_in[4];
  const float* kw   = (const float*)d_in[5];
  const float* vw   = (const float*)d_in[6];
  const float* vb   = (const float*)d_in[7];
  const float* pw   = (const float*)d_in[8];
  const float* pb   = (const float*)d_in[9];
  const float* ln2w = (const float*)d_in[10];
  const float* ln2b = (const float*)d_in[11];
  const float* w1   = (const float*)d_in[12];
  const float* w1b  = (const float*)d_in[13];
  const float* w2   = (const float*)d_in[14];
  const float* w2b  = (const float*)d_in[15];
  const float* ffw  = (const float*)d_in[16];
  const float* ffb  = (const float*)d_in[17];
  const float* w3   = (const float*)d_in[18];
  const float* w3b  = (const float*)d_in[19];

  char* ws = (char*)d_ws;
  size_t off = 0;
  auto alloc = [&](size_t bytes) -> char* {
    char* p = ws + off;
    off += (bytes + 255) & ~(size_t)255;
    return p;
  };
  u16* qwt = (u16*)alloc((size_t)768 * 768 * 2);
  u16* kwt = (u16*)alloc((size_t)768 * 768 * 2);
  u16* vwt = (u16*)alloc((size_t)768 * 768 * 2);
  u16* pwt = (u16*)alloc((size_t)768 * 768 * 2);
  u16* w1t = (u16*)alloc((size_t)2048 * 768 * 2);
  u16* w2t = (u16*)alloc((size_t)2048 * 768 * 2);
  u16* w3t = (u16*)alloc((size_t)768 * 2048 * 2);
  float* ct = (float*)alloc((size_t)196 * 64 * 4);
  float* st = (float*)alloc((size_t)196 * 64 * 4);
  u16* xw   = (u16*)alloc((size_t)T2 * C * 2);  // LN1 out; reused as h2 (LN2 out)
  u16* qbuf = (u16*)alloc((size_t)T2 * C * 2);  // q; attn out in-place; h1c chunk
  u16* kbuf = (u16*)alloc((size_t)T2 * C * 2);  // k; h2c chunk
  u16* vbuf = (u16*)alloc((size_t)T2 * C * 2);  // v
  u16* h2   = xw;
  u16* h1c  = qbuf;  // 8192*2048*2 = 33.5MB <= 50.3MB
  u16* h2c  = kbuf;
  float* x2 = (float*)d_out;  // f32 residual stream lives in d_out

  transpose_cvt_k<<<(768 * 768 + 255) / 256, 256, 0, stream>>>(qw, qwt, 768, 768);
  transpose_cvt_k<<<(768 * 768 + 255) / 256, 256, 0, stream>>>(kw, kwt, 768, 768);
  transpose_cvt_k<<<(768 * 768 + 255) / 256, 256, 0, stream>>>(vw, vwt, 768, 768);
  transpose_cvt_k<<<(768 * 768 + 255) / 256, 256, 0, stream>>>(pw, pwt, 768, 768);
  transpose_cvt_k<<<(768 * 2048 + 255) / 256, 256, 0, stream>>>(w1, w1t, 768, 2048);
  transpose_cvt_k<<<(768 * 2048 + 255) / 256, 256, 0, stream>>>(w2, w2t, 768, 2048);
  transpose_cvt_k<<<(2048 * 768 + 255) / 256, 256, 0, stream>>>(w3, w3t, 2048, 768);
  rope_tables_k<<<(196 * 32 + 255) / 256, 256, 0, stream>>>(ct, st);

  // attention half (flat tokens)
  ln_k<<<T2, 256, 0, stream>>>(x, ln1w, ln1b, xw);
  dim3 g1(T2 / 128, 6);
  gemm_k<0><<<g1, 256, 0, stream>>>(xw, qwt, qb, qbuf, nullptr, T2, 768, 768);
  gemm_k<0><<<g1, 256, 0, stream>>>(xw, kwt, nullptr, kbuf, nullptr, T2, 768, 768);
  gemm_k<0><<<g1, 256, 0, stream>>>(xw, vwt, vb, vbuf, nullptr, T2, 768, 768);
  rope_apply_k<<<(T2 * 384) / 256, 256, 0, stream>>>(qbuf, kbuf, ct, st);
  attn_mfma_k<<<200 * 12, 256, 0, stream>>>(qbuf, kbuf, vbuf, vb);
  gemm_k<2><<<g1, 256, 0, stream>>>(qbuf, pwt, pb, x2, x, T2, 768, 768);

  // FFN half, chunked to cap workspace
  ln_k<<<T2, 256, 0, stream>>>(x2, ln2w, ln2b, h2);
  for (int cidx = 0; cidx < T2 / CHUNK; ++cidx) {
    const u16* hrow = h2 + (size_t)cidx * CHUNK * C;
    dim3 g2(CHUNK / 128, 16);
    gemm_k<0><<<g2, 256, 0, stream>>>(hrow, w1t, w1b, h1c, nullptr, CHUNK, HID, 768);
    gemm_k<0><<<g2, 256, 0, stream>>>(hrow, w2t, w2b, h2c, nullptr, CHUNK, HID, 768);
    swiglu_ln_k<<<CHUNK, 256, 0, stream>>>(h1c, h2c, ffw, ffb, h1c);
    dim3 g3(CHUNK / 128, 6);
    gemm_k<2><<<g3, 256, 0, stream>>>(h1c, w3t, w3b, x2 + (size_t)cidx * CHUNK * C,
                                      x2 + (size_t)cidx * CHUNK * C, CHUNK, 768, 2048);
  }
}

// Round 4
// 1107.319 us; speedup vs baseline: 1.8081x; 1.3145x over previous
//
#include <hip/hip_runtime.h>
#include <hip/hip_bf16.h>
#include <stdint.h>

typedef unsigned short u16;
typedef unsigned int u32;
typedef __attribute__((ext_vector_type(4))) float f32x4;
typedef __attribute__((ext_vector_type(8))) short s16x8;
typedef __attribute__((ext_vector_type(4))) u32 u32x4;

#define DEV __device__ __forceinline__
#define AS1 __attribute__((address_space(1)))
#define AS3 __attribute__((address_space(3)))

// x: (8,64,64,768) flat tokens T2=32768. ws=14 windows; pads handled analytically
// (pad k == 0 exactly -> logit 0; pad v == v_b exactly; pad queries discarded).
constexpr int T2 = 8 * 64 * 64;
constexpr int C = 768;
constexpr int HID = 2048;
constexpr int CHUNK = 8192;   // FFN row chunk
constexpr int QKVS = 2304;    // fused qkv row stride

DEV float blo(u32 u) { return __uint_as_float(u << 16); }
DEV float bhi(u32 u) { return __uint_as_float(u & 0xffff0000u); }
DEV u16 f2bf(float f) {
  u32 x = __float_as_uint(f);
  u32 r = x + 0x7fffu + ((x >> 16) & 1u);
  return (u16)(r >> 16);
}
DEV u32 pack2(float a, float b) { return (u32)f2bf(a) | ((u32)f2bf(b) << 16); }
DEV u32 cvtpk(float lo, float hi) {  // bf16(lo) | bf16(hi)<<16, RNE (T12, m214v22)
  u32 r;
  asm("v_cvt_pk_bf16_f32 %0, %1, %2" : "=v"(r) : "v"(lo), "v"(hi));
  return r;
}

DEV void reduce2(float& s, float& q) {
#pragma unroll
  for (int o = 32; o > 0; o >>= 1) {
    s += __shfl_down(s, o);
    q += __shfl_down(q, o);
  }
  __shared__ float ps[8];
  int wave = threadIdx.x >> 6, lane = threadIdx.x & 63;
  if (lane == 0) { ps[wave] = s; ps[4 + wave] = q; }
  __syncthreads();
  s = ps[0] + ps[1] + ps[2] + ps[3];
  q = ps[4] + ps[5] + ps[6] + ps[7];
}

// ---- tiled transpose + f32->bf16: dst[(n*rs+ro)*K + k] = bf16(src[k*N+n]) ----
__global__ __launch_bounds__(256) void transpose_cvt_tiled_k(
    const float* __restrict__ src, u16* __restrict__ dst, int K, int N, int rs, int ro) {
  __shared__ float t[32][33];
  int k0 = blockIdx.x * 32, n0 = blockIdx.y * 32;
  int tx = threadIdx.x, ty = threadIdx.y;  // (32,8)
#pragma unroll
  for (int j = 0; j < 4; ++j)
    t[ty + j * 8][tx] = src[(size_t)(k0 + ty + j * 8) * N + n0 + tx];
  __syncthreads();
#pragma unroll
  for (int j = 0; j < 4; ++j) {
    int n = n0 + ty + j * 8;
    dst[((size_t)n * rs + ro) * K + k0 + tx] = f2bf(t[tx][ty + j * 8]);
  }
}

// combined bias vectors: qkvb[2304] = {qb, 0, vb}; w12b[4096] interleaved {w1b,w2b}
__global__ void build_biases_k(const float* __restrict__ qb, const float* __restrict__ vbb,
                               const float* __restrict__ w1b, const float* __restrict__ w2b,
                               float* __restrict__ qkvb, float* __restrict__ w12b) {
  int i = blockIdx.x * 256 + threadIdx.x;
  if (i < 2304)
    qkvb[i] = i < 768 ? qb[i] : (i < 1536 ? 0.f : vbb[i - 1536]);
  int j = i - 2304;
  if (j >= 0 && j < 4096) w12b[j] = (j & 1) ? w2b[j >> 1] : w1b[j >> 1];
}

// rope tables ct/st [196][64]
__global__ void rope_tables_k(float* __restrict__ ct, float* __restrict__ st) {
  int i = blockIdx.x * 256 + threadIdx.x;
  if (i >= 196 * 32) return;
  int n = i >> 5, jp = i & 31;
  int d = jp << 1;
  int r = n / 14, c = n - r * 14;
  float pos, fj;
  if (d < 32) { pos = (float)r * (16.f / 14.f); fj = (float)(d >> 1); }
  else        { pos = (float)c * (16.f / 14.f); fj = (float)((d - 32) >> 1); }
  float fr = __expf(fj * (-2.f / 32.f) * logf(10000.f));
  float ang = pos * fr;
  float cv = cosf(ang), sv = sinf(ang);
  ct[n * 64 + d] = cv; ct[n * 64 + d + 1] = cv;
  st[n * 64 + d] = sv; st[n * 64 + d + 1] = sv;
}

// LN rows of 768: f32 in -> bf16 out
__global__ __launch_bounds__(256) void ln_k(const float* __restrict__ in,
    const float* __restrict__ w, const float* __restrict__ bb, u16* __restrict__ out) {
  size_t row = blockIdx.x;
  int tid = threadIdx.x;
  const float* xr = in + row * C;
  float v0 = xr[tid], v1 = xr[tid + 256], v2 = xr[tid + 512];
  float s = v0 + v1 + v2, q = v0 * v0 + v1 * v1 + v2 * v2;
  reduce2(s, q);
  float mu = s * (1.f / 768.f), var = q * (1.f / 768.f) - mu * mu;
  float rs = rsqrtf(var + 1e-6f);
  u16* orow = out + row * C;
  orow[tid]       = f2bf((v0 - mu) * rs * w[tid]       + bb[tid]);
  orow[tid + 256] = f2bf((v1 - mu) * rs * w[tid + 256] + bb[tid + 256]);
  orow[tid + 512] = f2bf((v2 - mu) * rs * w[tid + 512] + bb[tid + 512]);
}

// ---- bf16 MFMA GEMM: Cout[M,Nn] = A[M,K](lda) * Bt[Nn,K]^T, 128x128 tile, BK=64 ----
// M, Nn multiples of 128 (callers guarantee). EPI 0: +bias -> bf16 ; EPI 2: +bias+resid -> f32
template <int EPI>
__global__ __launch_bounds__(256) void gemm_k(
    const u16* __restrict__ A, const u16* __restrict__ Bt,
    const float* __restrict__ bias, void* __restrict__ Cout,
    const float* __restrict__ resid, int M, int Nn, int K, int lda) {
  __shared__ u16 As[128 * 64];
  __shared__ u16 Bs[128 * 64];
  const int tid = threadIdx.x;
  const int wave = tid >> 6, lane = tid & 63;
  const int wm = wave >> 1, wn = wave & 1;
  const int tm = blockIdx.x, tn = blockIdx.y;
  const int l16 = lane & 15, lq = lane >> 4;

  f32x4 acc[4][4];
#pragma unroll
  for (int a = 0; a < 4; ++a)
#pragma unroll
    for (int b = 0; b < 4; ++b)
#pragma unroll
      for (int e = 0; e < 4; ++e) acc[a][b][e] = 0.f;

  const int nk = K >> 6;
  for (int kt = 0; kt < nk; ++kt) {
    const int k0 = kt << 6;
#pragma unroll
    for (int i = 0; i < 4; ++i) {
      int row = (((wave << 2) + i) << 3) + (lane >> 3);
      int cl = (lane & 7) ^ (row & 7);  // pre-swizzled source chunk (m173 pattern)
      const u16* sa = A + (size_t)(tm * 128 + row) * lda + k0 + cl * 8;
      __builtin_amdgcn_global_load_lds((const AS1 u32*)sa,
          (AS3 u32*)(As + (((wave << 2) + i) << 9)), 16, 0, 0);
      const u16* sb = Bt + (size_t)(tn * 128 + row) * K + k0 + cl * 8;
      __builtin_amdgcn_global_load_lds((const AS1 u32*)sb,
          (AS3 u32*)(Bs + (((wave << 2) + i) << 9)), 16, 0, 0);
    }
    asm volatile("s_waitcnt vmcnt(0)" ::: "memory");
    __syncthreads();
#pragma unroll
    for (int ks = 0; ks < 2; ++ks) {
      s16x8 af[4], bfr[4];
#pragma unroll
      for (int mf = 0; mf < 4; ++mf) {
        int row = (wm << 6) + (mf << 4) + l16;
        int sc = ((ks << 2) + lq) ^ (row & 7);
        af[mf] = *(const s16x8*)(As + row * 64 + sc * 8);
      }
#pragma unroll
      for (int nf = 0; nf < 4; ++nf) {
        int row = (wn << 6) + (nf << 4) + l16;
        int sc = ((ks << 2) + lq) ^ (row & 7);
        bfr[nf] = *(const s16x8*)(Bs + row * 64 + sc * 8);
      }
#pragma unroll
      for (int mf = 0; mf < 4; ++mf)
#pragma unroll
        for (int nf = 0; nf < 4; ++nf)
          acc[mf][nf] =
              __builtin_amdgcn_mfma_f32_16x16x32_bf16(af[mf], bfr[nf], acc[mf][nf], 0, 0, 0);
    }
    __syncthreads();
  }

  // C/D layout: col=lane&15, row=(lane>>4)*4+reg (m89-verified)
#pragma unroll
  for (int nf = 0; nf < 4; ++nf) {
    int col = (tn << 7) + (wn << 6) + (nf << 4) + l16;
    float bs = bias ? bias[col] : 0.f;
#pragma unroll
    for (int mf = 0; mf < 4; ++mf) {
      int rbase = (tm << 7) + (wm << 6) + (mf << 4) + (lq << 2);
      if constexpr (EPI == 0) {
        u32 p01 = cvtpk(acc[mf][nf][0] + bs, acc[mf][nf][1] + bs);
        u32 p23 = cvtpk(acc[mf][nf][2] + bs, acc[mf][nf][3] + bs);
        u16* cp = (u16*)Cout + (size_t)rbase * Nn + col;
        cp[0] = (u16)p01;
        cp[Nn] = (u16)(p01 >> 16);
        cp[2 * Nn] = (u16)p23;
        cp[3 * Nn] = (u16)(p23 >> 16);
      } else {
#pragma unroll
        for (int j = 0; j < 4; ++j) {
          size_t idx = (size_t)(rbase + j) * Nn + col;
          ((float*)Cout)[idx] = resid[idx] + acc[mf][nf][j] + bs;
        }
      }
    }
  }
}

// RoPE in-place on fused qkv (q scale folded); q at +0, k at +768
__global__ __launch_bounds__(256) void rope_apply_k(u16* __restrict__ qkv,
    const float* __restrict__ ct, const float* __restrict__ st) {
  int i = blockIdx.x * 256 + threadIdx.x;
  if (i >= T2 * 384) return;
  int t = i / 384, p = i - t * 384;
  int h = p >> 5, pr = p & 31;
  int d = pr << 1;
  int rem = t & 4095;
  int gh = rem >> 6, gw = rem & 63;
  int n = (gh % 14) * 14 + (gw % 14);  // window-local position
  float c = ct[n * 64 + d], s = st[n * 64 + d];
  size_t e = (size_t)t * QKVS + (h << 6) + d;
  u32* qp = (u32*)(qkv + e);
  u32 uq = *qp;
  float q0 = blo(uq), q1 = bhi(uq);
  *qp = pack2((q0 * c - q1 * s) * 0.125f, (q1 * c + q0 * s) * 0.125f);
  u32* kp = (u32*)(qkv + e + 768);
  u32 uk = *kp;
  float k0 = blo(uk), k1 = bhi(uk);
  *kp = pack2(k0 * c - k1 * s, k1 * c + k0 * s);
}

// ---- MFMA attention on fused qkv (row stride QKVS): block = (window, head) ----
__global__ __launch_bounds__(256) void attn_mfma_k(u16* __restrict__ qkv,
    const float* __restrict__ vb) {
  __shared__ u16 Ks[208 * 64];   // swizzled: byte = (key*128 + d*2) ^ ((key&7)<<4)
  __shared__ u16 Vt[64 * 224];   // swizzled: byte = (d*448 + key*2) ^ ((d&7)<<4)
  __shared__ u16 Pl[4 * 16 * 40];
  u16* q = qkv;
  const u16* k = qkv + 768;
  const u16* v = qkv + 1536;
  int wid = blockIdx.x / 12, h = blockIdx.x - wid * 12;
  int bi = wid / 25, wr = wid - bi * 25;
  int hi = wr / 5, wj = wr - hi * 5;
  int rh = (hi == 4) ? 8 : 14, rw = (wj == 4) ? 8 : 14;
  int nv = rh * rw;
  int nk16 = (nv + 15) >> 4;
  int kvfull = nk16 >> 1;
  int nsteps = kvfull + (nk16 & 1);
  int vcols = ((nk16 + 1) >> 1) << 5;
  int tid = threadIdx.x;
  int rowbase = (bi * 64 + hi * 14) * 64 + wj * 14;

  for (int idx = tid; idx < nk16 * 128; idx += 256) {
    int key = idx >> 3, c = idx & 7;
    u32x4 val = {0, 0, 0, 0};
    if (key < nv) {
      int nr = key / rw, nc = key - nr * rw;
      size_t off = (size_t)(rowbase + nr * 64 + nc) * QKVS + (h << 6) + c * 8;
      val = *(const u32x4*)(k + off);
    }
    int byte = (key * 128 + c * 16) ^ ((key & 7) << 4);
    *(u32x4*)(Ks + (byte >> 1)) = val;
  }
  for (int idx = tid; idx < vcols * 32; idx += 256) {
    int key = idx >> 5, dp = idx & 31;
    int d = dp << 1;
    u32 val;
    if (key < nv) {
      int nr = key / rw, nc = key - nr * rw;
      size_t off = (size_t)(rowbase + nr * 64 + nc) * QKVS + (h << 6) + d;
      val = *(const u32*)(v + off);
    } else {
      val = pack2(vb[(h << 6) + d], vb[(h << 6) + d + 1]);
    }
    int b0 = (d * 448 + key * 2) ^ ((d & 7) << 4);
    int b1 = ((d + 1) * 448 + key * 2) ^ (((d + 1) & 7) << 4);
    Vt[b0 >> 1] = (u16)(val & 0xffffu);
    Vt[b1 >> 1] = (u16)(val >> 16);
  }
  __syncthreads();

  int wave = tid >> 6, lane = tid & 63;
  int l16 = lane & 15, lq = lane >> 4;
  u16* Pw = Pl + wave * 640;
  float vbr[4];
#pragma unroll
  for (int dt = 0; dt < 4; ++dt) vbr[dt] = vb[(h << 6) + dt * 16 + l16];

  int mtiles = (nv + 15) >> 4;
  for (int mt = wave; mt < mtiles; mt += 4) {
    s16x8 a[2];
    {
      int qi = mt * 16 + l16;
      if (qi >= nv) qi = nv - 1;
      int nr = qi / rw, nc = qi - nr * rw;
      const u16* qp = q + (size_t)(rowbase + nr * 64 + nc) * QKVS + (h << 6);
      a[0] = *(const s16x8*)(qp + lq * 8);
      a[1] = *(const s16x8*)(qp + 32 + lq * 8);
    }
    f32x4 O[4];
#pragma unroll
    for (int dt = 0; dt < 4; ++dt)
#pragma unroll
      for (int j = 0; j < 4; ++j) O[dt][j] = 0.f;
    float mrow[4] = {-3.0e38f, -3.0e38f, -3.0e38f, -3.0e38f};
    float lrow[4] = {0.f, 0.f, 0.f, 0.f};

    for (int kv = 0; kv < nsteps; ++kv) {
      const bool full = kv < kvfull;
      const int keyb = kv << 5;
      f32x4 s0 = {0.f, 0.f, 0.f, 0.f}, s1 = {0.f, 0.f, 0.f, 0.f};
      int key0 = keyb + l16, key1 = key0 + 16;
#pragma unroll
      for (int s = 0; s < 2; ++s) {
        int byte0 = (key0 * 128 + s * 64 + lq * 16) ^ ((key0 & 7) << 4);
        s16x8 b0 = *(const s16x8*)(Ks + (byte0 >> 1));
        s0 = __builtin_amdgcn_mfma_f32_16x16x32_bf16(a[s], b0, s0, 0, 0, 0);
        if (full) {
          int byte1 = (key1 * 128 + s * 64 + lq * 16) ^ ((key1 & 7) << 4);
          s16x8 b1 = *(const s16x8*)(Ks + (byte1 >> 1));
          s1 = __builtin_amdgcn_mfma_f32_16x16x32_bf16(a[s], b1, s1, 0, 0, 0);
        }
      }
      float pc[4];
#pragma unroll
      for (int j = 0; j < 4; ++j) {
        float mv = full ? fmaxf(s0[j], s1[j]) : s0[j];
        mv = fmaxf(mv, __shfl_xor(mv, 1));
        mv = fmaxf(mv, __shfl_xor(mv, 2));
        mv = fmaxf(mv, __shfl_xor(mv, 4));
        mv = fmaxf(mv, __shfl_xor(mv, 8));
        float nm = fmaxf(mrow[j], mv);
        pc[j] = __expf(mrow[j] - nm);
        mrow[j] = nm;
      }
#pragma unroll
      for (int j = 0; j < 4; ++j) {
        float p0 = (key0 < 196) ? __expf(s0[j] - mrow[j]) : 0.f;
        float p1 = (full && key1 < 196) ? __expf(s1[j] - mrow[j]) : 0.f;
        float rs = p0 + p1;
        rs += __shfl_xor(rs, 1);
        rs += __shfl_xor(rs, 2);
        rs += __shfl_xor(rs, 4);
        rs += __shfl_xor(rs, 8);
        lrow[j] = lrow[j] * pc[j] + rs;
        Pw[(lq * 4 + j) * 40 + l16] = f2bf(p0);
        Pw[(lq * 4 + j) * 40 + l16 + 16] = f2bf(p1);
      }
#pragma unroll
      for (int dt = 0; dt < 4; ++dt)
#pragma unroll
        for (int j = 0; j < 4; ++j) O[dt][j] *= pc[j];
      s16x8 pa = *(const s16x8*)(Pw + l16 * 40 + lq * 8);
#pragma unroll
      for (int dt = 0; dt < 4; ++dt) {
        int d = dt * 16 + l16;
        int vbyte = (d * 448 + keyb * 2 + lq * 16) ^ ((d & 7) << 4);
        s16x8 bv = *(const s16x8*)(Vt + (vbyte >> 1));
        O[dt] = __builtin_amdgcn_mfma_f32_16x16x32_bf16(pa, bv, O[dt], 0, 0, 0);
      }
    }
    int Prem = 196 - (nk16 << 4);
    if (Prem > 0) {
#pragma unroll
      for (int j = 0; j < 4; ++j) {
        float nm = fmaxf(mrow[j], 0.f);
        float pc = __expf(mrow[j] - nm);
        float pp = __expf(-nm) * (float)Prem;
        lrow[j] = lrow[j] * pc + pp;
#pragma unroll
        for (int dt = 0; dt < 4; ++dt) O[dt][j] = O[dt][j] * pc + pp * vbr[dt];
      }
    }
#pragma unroll
    for (int j = 0; j < 4; ++j) {
      int qi = mt * 16 + lq * 4 + j;
      if (qi < nv) {
        float inv = 1.f / lrow[j];
        int nr = qi / rw, nc = qi - nr * rw;
        u16* op = q + (size_t)(rowbase + nr * 64 + nc) * QKVS + (h << 6);
#pragma unroll
        for (int dt = 0; dt < 4; ++dt) op[dt * 16 + l16] = f2bf(O[dt][j] * inv);
      }
    }
  }
}

// SwiGLU + LN over 2048; input h12 interleaved [rows][4096] (even=w1 out, odd=w2 out)
__global__ __launch_bounds__(256) void swiglu_ln_k(const u16* __restrict__ h12,
    const float* __restrict__ w, const float* __restrict__ bb, u16* __restrict__ out) {
  size_t row = blockIdx.x;
  int tid = threadIdx.x;
  const u32x4 ua = *(const u32x4*)(h12 + row * 4096 + tid * 16);
  const u32x4 ub = *(const u32x4*)(h12 + row * 4096 + tid * 16 + 8);
  u32 pp[8] = {ua.x, ua.y, ua.z, ua.w, ub.x, ub.y, ub.z, ub.w};
  float g[8];
  float s = 0.f, qq = 0.f;
#pragma unroll
  for (int j = 0; j < 8; ++j) {
    float a = blo(pp[j]), b = bhi(pp[j]);  // (h1_c, h2_c) in one u32
    float sl = a / (1.f + __expf(-a));
    g[j] = sl * b;
    s += g[j];
    qq += g[j] * g[j];
  }
  reduce2(s, qq);
  float mu = s * (1.f / 2048.f);
  float var = qq * (1.f / 2048.f) - mu * mu;
  float rs = rsqrtf(var + 1e-6f);
  const float* wp = w + tid * 8;
  const float* bp = bb + tid * 8;
  u32 o4[4];
#pragma unroll
  for (int j = 0; j < 4; ++j) {
    float o0 = (g[2 * j] - mu) * rs * wp[2 * j] + bp[2 * j];
    float o1 = (g[2 * j + 1] - mu) * rs * wp[2 * j + 1] + bp[2 * j + 1];
    o4[j] = cvtpk(o0, o1);
  }
  *(u32x4*)(out + row * HID + tid * 8) = (u32x4){o4[0], o4[1], o4[2], o4[3]};
}

extern "C" void kernel_launch(void* const* d_in, const int* in_sizes, int n_in,
                              void* d_out, int out_size, void* d_ws, size_t ws_size,
                              hipStream_t stream) {
  const float* x    = (const float*)d_in[0];
  const float* ln1w = (const float*)d_in[1];
  const float* ln1b = (const float*)d_in[2];
  const float* qw   = (const float*)d_in[3];
  const float* qb   = (const float*)d_in[4];
  const float* kw   = (const float*)d_in[5];
  const float* vw   = (const float*)d_in[6];
  const float* vb   = (const float*)d_in[7];
  const float* pw   = (const float*)d_in[8];
  const float* pb   = (const float*)d_in[9];
  const float* ln2w = (const float*)d_in[10];
  const float* ln2b = (const float*)d_in[11];
  const float* w1   = (const float*)d_in[12];
  const float* w1b  = (const float*)d_in[13];
  const float* w2   = (const float*)d_in[14];
  const float* w2b  = (const float*)d_in[15];
  const float* ffw  = (const float*)d_in[16];
  const float* ffb  = (const float*)d_in[17];
  const float* w3   = (const float*)d_in[18];
  const float* w3b  = (const float*)d_in[19];

  char* ws = (char*)d_ws;
  size_t off = 0;
  auto alloc = [&](size_t bytes) -> char* {
    char* p = ws + off;
    off += (bytes + 255) & ~(size_t)255;
    return p;
  };
  u16* qkvwt = (u16*)alloc((size_t)QKVS * 768 * 2);   // [2304][768]
  u16* pwt   = (u16*)alloc((size_t)768 * 768 * 2);
  u16* w12t  = (u16*)alloc((size_t)4096 * 768 * 2);   // interleaved cols
  u16* w3t   = (u16*)alloc((size_t)768 * 2048 * 2);
  float* qkvb = (float*)alloc((size_t)QKVS * 4);
  float* w12b = (float*)alloc((size_t)4096 * 4);
  float* ct = (float*)alloc((size_t)196 * 64 * 4);
  float* st = (float*)alloc((size_t)196 * 64 * 4);
  u16* xw  = (u16*)alloc((size_t)T2 * C * 2);     // LN1 out; reused as h2 (LN2 out)
  u16* qkv = (u16*)alloc((size_t)T2 * QKVS * 2);  // fused q|k|v; FFN arena after proj
  u16* h12c = qkv;                                 // [8192][4096] = 67.1MB
  u16* hswc = qkv + (size_t)CHUNK * 4096;          // [8192][2048] = 33.6MB
  float* x2 = (float*)d_out;                       // f32 residual stream in d_out

  dim3 tb(32, 8);
  transpose_cvt_tiled_k<<<dim3(24, 24), tb, 0, stream>>>(qw, qkvwt, 768, 768, 1, 0);
  transpose_cvt_tiled_k<<<dim3(24, 24), tb, 0, stream>>>(kw, qkvwt + (size_t)768 * 768, 768, 768, 1, 0);
  transpose_cvt_tiled_k<<<dim3(24, 24), tb, 0, stream>>>(vw, qkvwt + (size_t)1536 * 768, 768, 768, 1, 0);
  transpose_cvt_tiled_k<<<dim3(24, 24), tb, 0, stream>>>(pw, pwt, 768, 768, 1, 0);
  transpose_cvt_tiled_k<<<dim3(24, 64), tb, 0, stream>>>(w1, w12t, 768, 2048, 2, 0);
  transpose_cvt_tiled_k<<<dim3(24, 64), tb, 0, stream>>>(w2, w12t, 768, 2048, 2, 1);
  transpose_cvt_tiled_k<<<dim3(64, 24), tb, 0, stream>>>(w3, w3t, 2048, 768, 1, 0);
  build_biases_k<<<25, 256, 0, stream>>>(qb, vb, w1b, w2b, qkvb, w12b);
  rope_tables_k<<<(196 * 32 + 255) / 256, 256, 0, stream>>>(ct, st);

  // attention half (flat tokens)
  ln_k<<<T2, 256, 0, stream>>>(x, ln1w, ln1b, xw);
  gemm_k<0><<<dim3(T2 / 128, QKVS / 128), 256, 0, stream>>>(
      xw, qkvwt, qkvb, qkv, nullptr, T2, QKVS, 768, 768);
  rope_apply_k<<<(T2 * 384) / 256, 256, 0, stream>>>(qkv, ct, st);
  attn_mfma_k<<<200 * 12, 256, 0, stream>>>(qkv, vb);
  gemm_k<2><<<dim3(T2 / 128, 6), 256, 0, stream>>>(
      qkv, pwt, pb, x2, x, T2, 768, 768, QKVS);

  // FFN half, chunked; arena aliases dead qkv
  ln_k<<<T2, 256, 0, stream>>>(x2, ln2w, ln2b, xw);
  for (int cidx = 0; cidx < T2 / CHUNK; ++cidx) {
    const u16* hrow = xw + (size_t)cidx * CHUNK * C;
    gemm_k<0><<<dim3(CHUNK / 128, 32), 256, 0, stream>>>(
        hrow, w12t, w12b, h12c, nullptr, CHUNK, 4096, 768, 768);
    swiglu_ln_k<<<CHUNK, 256, 0, stream>>>(h12c, ffw, ffb, hswc);
    gemm_k<2><<<dim3(CHUNK / 128, 6), 256, 0, stream>>>(
        hswc, w3t, w3b, x2 + (size_t)cidx * CHUNK * C,
        x2 + (size_t)cidx * CHUNK * C, CHUNK, 768, 2048, 2048);
  }
}